// Round 1
// 385.243 us; speedup vs baseline: 1.0036x; 1.0036x over previous
//
#include <hip/hip_runtime.h>
#include <hip/hip_bf16.h>

// Problem constants (reference): B=2, L=2048, D=256, H=8, DK=DV=32
// d_out = [ out (2*2048*256 f32) | attn (2*8*2048*2048 f32) ]

typedef __bf16 bf16;
typedef __bf16 bf16x8 __attribute__((ext_vector_type(8)));
typedef __bf16 bf16x4 __attribute__((ext_vector_type(4)));
typedef float  f32x4  __attribute__((ext_vector_type(4)));

#define MFMA16(a, b, c) __builtin_amdgcn_mfma_f32_16x16x32_bf16((a), (b), (c), 0, 0, 0)

__device__ __forceinline__ void split_bf16(float x, bf16& hi, bf16& lo) {
    hi = (bf16)x;
    lo = (bf16)(x - (float)hi);
}

// ---------------------------------------------------------------------------
// Kernel 1: weight prep.  Transpose + convert all weights once:
//   mat 0/1/2: wq/wk/wv [256k][256n] fp32 -> Wt hi/lo bf16 [n][k]
//   mat 3:     wfc      [256k][256c] fp32 -> wt bf16 [c][k]
// ---------------------------------------------------------------------------
__global__ __launch_bounds__(256) void prep_weights(
    const float* __restrict__ wq, const float* __restrict__ wk,
    const float* __restrict__ wv, const float* __restrict__ wfc,
    bf16* __restrict__ Wqh, bf16* __restrict__ Wql,
    bf16* __restrict__ Wkh, bf16* __restrict__ Wkl,
    bf16* __restrict__ Wvh, bf16* __restrict__ Wvl,
    bf16* __restrict__ wt)
{
    __shared__ float tile[32][33];
    const int mat = blockIdx.y;
    const float* src = (mat == 0) ? wq : (mat == 1) ? wk : (mat == 2) ? wv : wfc;
    const int bk = (blockIdx.x & 7) * 32;   // source row block (k)
    const int bc = (blockIdx.x >> 3) * 32;  // source col block (n)
    const int t = threadIdx.x;
    const int c = t & 31, r = t >> 5;
#pragma unroll
    for (int i = 0; i < 4; ++i) {
        int kk = r + i * 8;
        tile[kk][c] = src[(size_t)(bk + kk) * 256 + bc + c];
    }
    __syncthreads();
#pragma unroll
    for (int i = 0; i < 4; ++i) {
        int nn = r + i * 8;
        float x = tile[c][nn];
        size_t idx = (size_t)(bc + nn) * 256 + bk + c;
        if (mat == 3) {
            wt[idx] = (bf16)x;
        } else {
            bf16 h, l; split_bf16(x, h, l);
            bf16* H = (mat == 0) ? Wqh : (mat == 1) ? Wkh : Wvh;
            bf16* L = (mat == 0) ? Wql : (mat == 1) ? Wkl : Wvl;
            H[idx] = h; L[idx] = l;
        }
    }
}

// ---------------------------------------------------------------------------
// Kernel 2: projections, streaming (no LDS, no barriers).
// C[4096,256] = A[4096,256] @ W[256,256] for A in {q,k,v}; W pre-transposed
// hi/lo bf16 by prep_weights.  Split-bf16 MFMA, accumulation order identical
// to the previous LDS-staged version (bitwise-identical results).
// Outputs:
//   proj 0: Qhi/Qlo bf16 [bh][l][32]  (pre-scaled by 1/sqrt(32))
//   proj 1: Khi/Klo bf16 [bh][l][32]
//   proj 2: Vt bf16 [bh][32][l]  (transposed for PV B-fragments)
// ---------------------------------------------------------------------------
__global__ __launch_bounds__(256, 3) void proj_kernel(
    const float* __restrict__ qin, const float* __restrict__ kin, const float* __restrict__ vin,
    const bf16* __restrict__ Wqh, const bf16* __restrict__ Wql,
    const bf16* __restrict__ Wkh, const bf16* __restrict__ Wkl,
    const bf16* __restrict__ Wvh, const bf16* __restrict__ Wvl,
    bf16* __restrict__ Qhi, bf16* __restrict__ Qlo,
    bf16* __restrict__ Khi, bf16* __restrict__ Klo, bf16* __restrict__ Vt)
{
    const int proj = blockIdx.y;
    const int tr = blockIdx.x & 63;   // row tile (64 rows)
    const int tn = blockIdx.x >> 6;   // col tile (64 cols)
    const float* A  = (proj == 0) ? qin : (proj == 1) ? kin : vin;
    const bf16*  WH = (proj == 0) ? Wqh : (proj == 1) ? Wkh : Wvh;
    const bf16*  WL = (proj == 0) ? Wql : (proj == 1) ? Wkl : Wvl;

    const int t = threadIdx.x;
    const int lane = t & 63, w = t >> 6;
    const int m = lane & 15, g = lane >> 4;

    const int row0 = tr * 64 + ((w >> 1) << 5);
    const int col0 = tn * 64 + ((w & 1) << 5);

    f32x4 acc[2][2] = {};

#pragma unroll
    for (int ks = 0; ks < 8; ++ks) {
        const int k0 = ks * 32 + g * 8;
        bf16x8 ah[2], al[2], bh[2], bl[2];
#pragma unroll
        for (int rt = 0; rt < 2; ++rt) {
            const float* ap = &A[(size_t)(row0 + (rt << 4) + m) * 256 + k0];
            float4 f0 = *(const float4*)ap;
            float4 f1 = *(const float4*)(ap + 4);
            float xs[8] = {f0.x, f0.y, f0.z, f0.w, f1.x, f1.y, f1.z, f1.w};
#pragma unroll
            for (int j = 0; j < 8; ++j) {
                bf16 h, l; split_bf16(xs[j], h, l);
                ah[rt][j] = h; al[rt][j] = l;
            }
        }
#pragma unroll
        for (int nt = 0; nt < 2; ++nt) {
            size_t wi = (size_t)(col0 + (nt << 4) + m) * 256 + k0;
            bh[nt] = *(const bf16x8*)&WH[wi];
            bl[nt] = *(const bf16x8*)&WL[wi];
        }
#pragma unroll
        for (int rt = 0; rt < 2; ++rt)
#pragma unroll
            for (int nt = 0; nt < 2; ++nt) {
                acc[rt][nt] = MFMA16(ah[rt], bh[nt], acc[rt][nt]);
                acc[rt][nt] = MFMA16(ah[rt], bl[nt], acc[rt][nt]);
                acc[rt][nt] = MFMA16(al[rt], bh[nt], acc[rt][nt]);
            }
    }

    // epilogue: scatter into head-major layouts (hi/lo split for Q, K)
#pragma unroll
    for (int rt = 0; rt < 2; ++rt)
#pragma unroll
        for (int nt = 0; nt < 2; ++nt)
#pragma unroll
            for (int i = 0; i < 4; ++i) {
                int row = tr * 64 + ((w >> 1) << 5) + (rt << 4) + (g << 2) + i;
                int col = tn * 64 + ((w & 1) << 5) + (nt << 4) + m;
                float val = acc[rt][nt][i];
                int b = row >> 11, l2 = row & 2047;
                int hh = col >> 5, d = col & 31;
                int bh8 = b * 8 + hh;
                size_t idx = ((size_t)bh8 * 2048 + l2) * 32 + d;
                if (proj == 0) {
                    bf16 h, l; split_bf16(val * 0.17677669529663688f, h, l); // 1/sqrt(32)
                    Qhi[idx] = h; Qlo[idx] = l;
                } else if (proj == 1) {
                    bf16 h, l; split_bf16(val, h, l);
                    Khi[idx] = h; Klo[idx] = l;
                } else {
                    Vt[((size_t)bh8 * 32 + d) * 2048 + l2] = (bf16)val;
                }
            }
}

// ---------------------------------------------------------------------------
// Kernel 3: attention, fully wave-parallel, no barriers, no big LDS.
// Grid: 512 blocks = 16 (b,h) x 32 q-groups of 64 rows; each wave owns 16
// q-rows x all 2048 keys.
//   Pass 1: S^T = K.Q^T (split-bf16 MFMA, swapped operands so each lane holds
//           4 CONSECUTIVE keys of one q-row) -> rowsum in registers
//           (shfl-reduce across the 4 row-groups).
//   Pass 2: recompute S^T, exp, multiply by 1/rowsum, stream float4
//           nontemporal stores of attn; stage unnormalized exp through a
//           1.25 KB per-wave LDS tile (C-layout -> A-layout) and fuse PV MFMA.
// ---------------------------------------------------------------------------
__global__ __launch_bounds__(256, 2) void attn_kernel(
    const bf16* __restrict__ Qhi, const bf16* __restrict__ Qlo,
    const bf16* __restrict__ Khi, const bf16* __restrict__ Klo,
    const bf16* __restrict__ Vt,
    float* __restrict__ attn_out, bf16* __restrict__ out_h)
{
    __shared__ __align__(16) bf16 stage[4][2][16 * 40];  // per-wave, dbuf, row pad 40

    const int t = threadIdx.x, lane = t & 63, w = t >> 6;
    const int m = lane & 15, g = lane >> 4;
    const int bh = blockIdx.x >> 5;
    const int qb = ((blockIdx.x & 31) << 6) + (w << 4);  // this wave's 16 q-rows

    const bf16* Kh = Khi + ((size_t)bh << 16);
    const bf16* Kl = Klo + ((size_t)bh << 16);
    const bf16* Vb = Vt  + ((size_t)bh << 16);

    // Q B-fragments (fixed): B[n=q=m][k=g*8+j]
    const size_t qidx = (((size_t)bh << 11) + qb + m) * 32 + g * 8;
    const bf16x8 qh = *(const bf16x8*)&Qhi[qidx];
    const bf16x8 ql = *(const bf16x8*)&Qlo[qidx];

    // ---- pass 1: rowsum for q = m ----
    float rs = 0.f;
    for (int kt = 0; kt < 128; ++kt) {
        const size_t ki = (size_t)(kt * 16 + m) * 32 + g * 8;
        bf16x8 kh = *(const bf16x8*)&Kh[ki];
        bf16x8 kl = *(const bf16x8*)&Kl[ki];
        f32x4 s = {0.f, 0.f, 0.f, 0.f};
        s = MFMA16(kh, qh, s);
        s = MFMA16(kh, ql, s);
        s = MFMA16(kl, qh, s);
        rs += __expf(s[0]) + __expf(s[1]) + __expf(s[2]) + __expf(s[3]);
    }
    rs += __shfl_xor(rs, 16);
    rs += __shfl_xor(rs, 32);
    const float inv = __builtin_amdgcn_rcpf(rs);  // 1/rowsum for q = m (all lanes)

    // ---- pass 2: attn stores + fused PV ----
    f32x4 o0 = {0.f, 0.f, 0.f, 0.f}, o1 = {0.f, 0.f, 0.f, 0.f};
    float* ab = attn_out + ((size_t)(bh * 2048 + qb + m)) * 2048;  // row q = m

    for (int kt = 0; kt < 64; ++kt) {
        const int key0 = kt << 5;  // 32 keys per iteration (2 MFMA tiles)
        const size_t kia = (size_t)(key0 + m) * 32 + g * 8;
        const size_t kib = (size_t)(key0 + 16 + m) * 32 + g * 8;
        bf16x8 kha = *(const bf16x8*)&Kh[kia];
        bf16x8 kla = *(const bf16x8*)&Kl[kia];
        bf16x8 khb = *(const bf16x8*)&Kh[kib];
        bf16x8 klb = *(const bf16x8*)&Kl[kib];

        f32x4 sa = {0.f, 0.f, 0.f, 0.f}, sb = {0.f, 0.f, 0.f, 0.f};
        sa = MFMA16(kha, qh, sa); sa = MFMA16(kha, ql, sa); sa = MFMA16(kla, qh, sa);
        sb = MFMA16(khb, qh, sb); sb = MFMA16(khb, ql, sb); sb = MFMA16(klb, qh, sb);

        f32x4 ea, eb;
#pragma unroll
        for (int i = 0; i < 4; ++i) { ea[i] = __expf(sa[i]); eb[i] = __expf(sb[i]); }

        // normalized attn: lane holds keys key0+g*4.. (ea) and key0+16+g*4.. (eb), row q=m
        f32x4 na = {ea[0] * inv, ea[1] * inv, ea[2] * inv, ea[3] * inv};
        f32x4 nb = {eb[0] * inv, eb[1] * inv, eb[2] * inv, eb[3] * inv};
        __builtin_nontemporal_store(na, (f32x4*)&ab[key0 + (g << 2)]);
        __builtin_nontemporal_store(nb, (f32x4*)&ab[key0 + 16 + (g << 2)]);

        // stage unnormalized exp (bf16) C-layout -> A-layout for PV
        bf16x4 pa, pb;
#pragma unroll
        for (int i = 0; i < 4; ++i) { pa[i] = (bf16)ea[i]; pb[i] = (bf16)eb[i]; }
        bf16* sp = &stage[w][kt & 1][0];
        *(bf16x4*)&sp[m * 40 + (g << 2)] = pa;
        *(bf16x4*)&sp[m * 40 + 16 + (g << 2)] = pb;
        bf16x8 pf = *(const bf16x8*)&sp[m * 40 + (g << 3)];

        bf16x8 v0 = *(const bf16x8*)&Vb[(size_t)m * 2048 + key0 + (g << 3)];
        bf16x8 v1 = *(const bf16x8*)&Vb[(size_t)(m + 16) * 2048 + key0 + (g << 3)];
        o0 = MFMA16(pf, v0, o0);  // D[q=g*4+i][d=m]
        o1 = MFMA16(pf, v1, o1);  // D[q=g*4+i][d=m+16]
    }

    // epilogue: scale rows by their 1/rowsum and store out_h [b][l][h*32+d]
    const int b = bh >> 3, hh = bh & 7;
#pragma unroll
    for (int i = 0; i < 4; ++i) {
        float invq = __shfl(inv, (g << 2) + i);  // inv for q = g*4+i
        size_t base = ((size_t)b * 2048 + qb + (g << 2) + i) * 256 + hh * 32;
        out_h[base + m]      = (bf16)(o0[i] * invq);
        out_h[base + 16 + m] = (bf16)(o1[i] * invq);
    }
}

// ---------------------------------------------------------------------------
// Kernel 4: out = LN( out_h @ w_fc + residual ) with gamma/beta, eps=1e-6.
// ---------------------------------------------------------------------------
__global__ __launch_bounds__(256, 2) void fc_ln_kernel(
    const bf16* __restrict__ oh, const bf16* __restrict__ wt,
    const float* __restrict__ qres, const float* __restrict__ gamma,
    const float* __restrict__ beta, float* __restrict__ outp)
{
    __shared__ float tile[16][260];
    const int rbase = blockIdx.x << 4;
    const int t = threadIdx.x, lane = t & 63, w = t >> 6;
    const int m = lane & 15, g = lane >> 4;

    f32x4 acc[4] = {};
#pragma unroll
    for (int ks = 0; ks < 8; ++ks) {
        bf16x8 a = *(const bf16x8*)&oh[(size_t)(rbase + m) * 256 + ks * 32 + g * 8];
#pragma unroll
        for (int ct = 0; ct < 4; ++ct) {
            int col = (w << 6) + (ct << 4) + m;
            bf16x8 bb = *(const bf16x8*)&wt[(size_t)col * 256 + ks * 32 + g * 8];
            acc[ct] = MFMA16(a, bb, acc[ct]);
        }
    }
#pragma unroll
    for (int ct = 0; ct < 4; ++ct)
#pragma unroll
        for (int i = 0; i < 4; ++i) {
            int row = (g << 2) + i;
            int col = (w << 6) + (ct << 4) + m;
            tile[row][col] = acc[ct][i] + qres[(size_t)(rbase + row) * 256 + col];
        }
    __syncthreads();

#pragma unroll
    for (int rr = 0; rr < 4; ++rr) {
        int row = (w << 2) + rr;
        int c = lane << 2;
        float4 x = *(const float4*)&tile[row][c];
        float s  = x.x + x.y + x.z + x.w;
        float sq = x.x * x.x + x.y * x.y + x.z * x.z + x.w * x.w;
#pragma unroll
        for (int off = 1; off < 64; off <<= 1) {
            s  += __shfl_xor(s, off);
            sq += __shfl_xor(sq, off);
        }
        float mu   = s * (1.0f / 256.0f);
        float var  = sq * (1.0f / 256.0f) - mu * mu;
        float rstd = rsqrtf(var + 1e-6f);
        float4 gm = *(const float4*)&gamma[c];
        float4 bt = *(const float4*)&beta[c];
        float4 y;
        y.x = (x.x - mu) * rstd * gm.x + bt.x;
        y.y = (x.y - mu) * rstd * gm.y + bt.y;
        y.z = (x.z - mu) * rstd * gm.z + bt.z;
        y.w = (x.w - mu) * rstd * gm.w + bt.w;
        *(float4*)&outp[(size_t)(rbase + row) * 256 + c] = y;
    }
}

// ---------------------------------------------------------------------------
extern "C" void kernel_launch(void* const* d_in, const int* in_sizes, int n_in,
                              void* d_out, int out_size, void* d_ws, size_t ws_size,
                              hipStream_t stream)
{
    (void)in_sizes; (void)n_in; (void)out_size; (void)ws_size;

    const float* q   = (const float*)d_in[0];
    const float* k   = (const float*)d_in[1];
    const float* v   = (const float*)d_in[2];
    const float* wq  = (const float*)d_in[3];
    const float* wk  = (const float*)d_in[4];
    const float* wv  = (const float*)d_in[5];
    const float* wfc = (const float*)d_in[6];
    const float* gm  = (const float*)d_in[7];
    const float* bt  = (const float*)d_in[8];

    float* out  = (float*)d_out;
    float* attn = out + (size_t)2 * 2048 * 256;

    char* ws = (char*)d_ws;
    bf16* Qhi = (bf16*)(ws);                        // 2 MB  [16][2048][32]
    bf16* Qlo = (bf16*)(ws + ((size_t)2 << 20));    // 2 MB
    bf16* Khi = (bf16*)(ws + ((size_t)4 << 20));    // 2 MB
    bf16* Klo = (bf16*)(ws + ((size_t)6 << 20));    // 2 MB
    bf16* Vt  = (bf16*)(ws + ((size_t)8 << 20));    // 2 MB  [16][32][2048]
    bf16* oh  = (bf16*)(ws + ((size_t)10 << 20));   // 2 MB  [4096][256]
    bf16* wt  = (bf16*)(ws + ((size_t)12 << 20));   // 128 KB [256][256]
    bf16* Wqh = (bf16*)(ws + ((size_t)12 << 20) + (1 << 17));  // 128 KB each
    bf16* Wql = (bf16*)(ws + ((size_t)12 << 20) + (2 << 17));
    bf16* Wkh = (bf16*)(ws + ((size_t)12 << 20) + (3 << 17));
    bf16* Wkl = (bf16*)(ws + ((size_t)12 << 20) + (4 << 17));
    bf16* Wvh = (bf16*)(ws + ((size_t)12 << 20) + (5 << 17));
    bf16* Wvl = (bf16*)(ws + ((size_t)12 << 20) + (6 << 17));

    prep_weights<<<dim3(64, 4), 256, 0, stream>>>(wq, wk, wv, wfc,
                                                  Wqh, Wql, Wkh, Wkl, Wvh, Wvl, wt);
    proj_kernel<<<dim3(256, 3), 256, 0, stream>>>(q, k, v,
                                                  Wqh, Wql, Wkh, Wkl, Wvh, Wvl,
                                                  Qhi, Qlo, Khi, Klo, Vt);
    attn_kernel<<<512, 256, 0, stream>>>(Qhi, Qlo, Khi, Klo, Vt, attn, oh);
    fc_ln_kernel<<<256, 256, 0, stream>>>(oh, wt, q, gm, bt, out);
}